// Round 1
// 1364.026 us; speedup vs baseline: 1.0088x; 1.0088x over previous
//
#include <hip/hip_runtime.h>

typedef __bf16 bf16x8 __attribute__((ext_vector_type(8)));
typedef float  f32x4  __attribute__((ext_vector_type(4)));

#define NB 64      // attention tokens (B axis)
#define NC 512     // channels
#define NL 4096    // batched positions (L axis)
#define LT 16      // l-tile per workgroup: one 64B line per (b,c) row

// LDS regions, aliased in time (max 128 KiB):
//   phase1 stage: bf16 [LT][64 m][40 cc]  = 81920 B
//   P' matrix   : bf16 [LT][64 n][64 m]   = 131072 B
//   phase2 stage: bf16 [32 cc][1032]      = 66048 B

__global__ __launch_bounds__(512, 2)
void attn_prop_kernel(const float* __restrict__ x, float* __restrict__ out)
{
    __shared__ __align__(16) unsigned char smem_raw[131072];
    __bf16* const p_lds = (__bf16*)smem_raw;
    __bf16* const s1    = (__bf16*)smem_raw;
    __bf16* const s2    = (__bf16*)smem_raw;

    const int tid  = threadIdx.x;
    const int wave = tid >> 6;
    const int lane = tid & 63;
    const int quad = lane >> 4;
    const int c16  = lane & 15;
    const int l0   = blockIdx.x * LT;

    // Coalesced staging mapping: 4 consecutive lanes cover one 64 B (m,cc) row.
    // Each step r covers 128 rows; 16 steps cover the 64m x 32cc chunk.
    const int srow = tid >> 2;   // row-within-step (0..127)
    const int seg  = tid & 3;    // 16B segment within row: l = seg*4 .. seg*4+3

    // ================= phase 1: S = (A A^T)/sqrt(C); P' = softmax(S) + I ==========
    f32x4 acc[2][4][4];
#pragma unroll
    for (int ll = 0; ll < 2; ++ll)
#pragma unroll
        for (int i = 0; i < 4; ++i)
#pragma unroll
            for (int j = 0; j < 4; ++j)
                acc[ll][i][j] = (f32x4){0.f, 0.f, 0.f, 0.f};

    float4 R[16];   // cross-iteration prefetch buffer (64 VGPRs)

    // prologue: load chunk kc=0
#pragma unroll
    for (int r = 0; r < 16; ++r) {
        const int row = (r << 7) + srow;
        const int m = row >> 5, cc = row & 31;
        R[r] = *(const float4*)(x + ((m * NC + cc) * NL + l0) + (seg << 2));
    }

    for (int kc = 0; kc < 16; ++kc) {
        __syncthreads();   // prev iter frag reads done before restage
        // store chunk kc (held in R) to LDS
#pragma unroll
        for (int r = 0; r < 16; ++r) {
            const int row = (r << 7) + srow;
            const int m = row >> 5, cc = row & 31;
#pragma unroll
            for (int j = 0; j < 4; ++j)
                s1[((seg * 4 + j) * 64 + m) * 40 + cc] = (__bf16)R[r][j];
        }
        // issue prefetch of chunk kc+1; latency hides under MFMA + barriers
        if (kc < 15) {
            const int c0n = (kc + 1) * 32;
#pragma unroll
            for (int r = 0; r < 16; ++r) {
                const int row = (r << 7) + srow;
                const int m = row >> 5, cc = row & 31;
                R[r] = *(const float4*)(x + ((m * NC + c0n + cc) * NL + l0) + (seg << 2));
            }
        }
        __syncthreads();
#pragma unroll
        for (int ll = 0; ll < 2; ++ll) {
            const int l = wave * 2 + ll;
            bf16x8 a[4];
#pragma unroll
            for (int i = 0; i < 4; ++i)
                a[i] = *(const bf16x8*)(s1 + (l * 64 + i * 16 + c16) * 40 + quad * 8);
#pragma unroll
            for (int i = 0; i < 4; ++i)
#pragma unroll
                for (int j = 0; j < 4; ++j)
                    acc[ll][i][j] = __builtin_amdgcn_mfma_f32_16x16x32_bf16(
                        a[i], a[j], acc[ll][i][j], 0, 0, 0);
        }
    }

    // prefetch phase-2 chunk ch=0 NOW: hides under softmax + P' store + pf load
#pragma unroll
    for (int r = 0; r < 16; ++r) {
        const int row = (r << 7) + srow;
        const int m = row >> 5, cc = row & 31;
        R[r] = *(const float4*)(x + ((m * NC + cc) * NL + l0) + (seg << 2));
    }

    __syncthreads();   // all frag reads of s1 done; safe to overwrite with P'

    // softmax rows n = 16i + 4*quad + q; cols m = 16j + c16
    const float rs = 0.04419417382415922f;   // 1/sqrt(512)
#pragma unroll
    for (int ll = 0; ll < 2; ++ll) {
        const int l = wave * 2 + ll;
#pragma unroll
        for (int i = 0; i < 4; ++i) {
#pragma unroll
            for (int q = 0; q < 4; ++q) {
                float s[4];
#pragma unroll
                for (int j = 0; j < 4; ++j) s[j] = acc[ll][i][j][q] * rs;
                float rmax = fmaxf(fmaxf(s[0], s[1]), fmaxf(s[2], s[3]));
#pragma unroll
                for (int d = 1; d <= 8; d <<= 1)
                    rmax = fmaxf(rmax, __shfl_xor(rmax, d, 64));
                float e[4], rsum = 0.f;
#pragma unroll
                for (int j = 0; j < 4; ++j) { e[j] = __expf(s[j] - rmax); rsum += e[j]; }
#pragma unroll
                for (int d = 1; d <= 8; d <<= 1)
                    rsum += __shfl_xor(rsum, d, 64);
                const float inv = 1.0f / rsum;
                const int n = i * 16 + quad * 4 + q;
#pragma unroll
                for (int j = 0; j < 4; ++j) {
                    float p = e[j] * inv;
                    if (i == j && (quad * 4 + q) == c16) p += 1.0f;  // P' = P + I
                    p_lds[l * 4096 + n * 64 + j * 16 + c16] = (__bf16)p;
                }
            }
        }
    }
    __syncthreads();

    // phase-2 wave assignment: wave -> (n-tile iw, c-subtile jw), all 16 l per wave.
    const int iw = wave & 3;
    const int jw = wave >> 2;
    bf16x8 pf[16][2];   // P' A-fragments
#pragma unroll
    for (int l = 0; l < 16; ++l)
#pragma unroll
        for (int k2 = 0; k2 < 2; ++k2)
            pf[l][k2] = *(const bf16x8*)(p_lds + l * 4096 + (iw * 16 + c16) * 64 + k2 * 32 + quad * 8);
    __syncthreads();   // pf loaded; s2 may overwrite P' region

    // ================= phase 2: out = P' A (chunked over c) =======================
    for (int ch = 0; ch < 16; ++ch) {
        // store chunk ch (held in R) to LDS
#pragma unroll
        for (int r = 0; r < 16; ++r) {
            const int row = (r << 7) + srow;
            const int m = row >> 5, cc = row & 31;
#pragma unroll
            for (int j = 0; j < 4; ++j)
                s2[cc * 1032 + (seg * 4 + j) * 64 + m] = (__bf16)R[r][j];
        }
        // issue prefetch of chunk ch+1; latency hides under MFMA + out-stores
        if (ch < 15) {
            const int c0n = (ch + 1) * 32;
#pragma unroll
            for (int r = 0; r < 16; ++r) {
                const int row = (r << 7) + srow;
                const int m = row >> 5, cc = row & 31;
                R[r] = *(const float4*)(x + ((m * NC + c0n + cc) * NL + l0) + (seg << 2));
            }
        }
        __syncthreads();

        const int c0 = ch * 32;
        const int cg = c0 + jw * 16 + c16;
        // two l-halves of 8, so live acc2 stays at 32 VGPRs
#pragma unroll
        for (int h = 0; h < 2; ++h) {
            f32x4 acc2[8];
#pragma unroll
            for (int u = 0; u < 8; ++u) {
                const int l = h * 8 + u;
                f32x4 a2 = (f32x4){0.f, 0.f, 0.f, 0.f};
#pragma unroll
                for (int k2 = 0; k2 < 2; ++k2) {
                    bf16x8 b = *(const bf16x8*)(s2 + (jw * 16 + c16) * 1032 + l * 64 + k2 * 32 + quad * 8);
                    a2 = __builtin_amdgcn_mfma_f32_16x16x32_bf16(pf[l][k2], b, a2, 0, 0, 0);
                }
                acc2[u] = a2;
            }
#pragma unroll
            for (int q = 0; q < 4; ++q) {
                const int n = iw * 16 + quad * 4 + q;
                float* dst = out + ((n * NC + cg) * NL + l0) + h * 8;
                float4 w;
                w.x = acc2[0][q]; w.y = acc2[1][q]; w.z = acc2[2][q]; w.w = acc2[3][q];
                ((float4*)dst)[0] = w;
                w.x = acc2[4][q]; w.y = acc2[5][q]; w.z = acc2[6][q]; w.w = acc2[7][q];
                ((float4*)dst)[1] = w;
            }
        }
        __syncthreads();   // B-frag reads done before next restage
    }
}

extern "C" void kernel_launch(void* const* d_in, const int* in_sizes, int n_in,
                              void* d_out, int out_size, void* d_ws, size_t ws_size,
                              hipStream_t stream)
{
    const float* x = (const float*)d_in[0];
    float* o = (float*)d_out;
    attn_prop_kernel<<<dim3(NL / LT), dim3(512), 0, stream>>>(x, o);
}

// Round 2
// 1333.224 us; speedup vs baseline: 1.0321x; 1.0231x over previous
//
#include <hip/hip_runtime.h>

typedef __bf16 bf16x8 __attribute__((ext_vector_type(8)));
typedef float  f32x4  __attribute__((ext_vector_type(4)));

#define NB 64      // attention tokens (B axis)
#define NC 512     // channels
#define NL 4096    // batched positions (L axis)
#define LT 16      // l-tile per workgroup

// LDS regions, aliased in time (128 KiB total):
//   phase1 stage: bf16 [16 l][64 m][40 cc]  = 81920 B
//   P' matrix   : bf16 [16 l][64 n][64 m]   = 131072 B
//   phase2 stage: bf16 [32 cc][1032]        = 66048 B, placed over P' l=0..8 region
//                 (l<=8 P' is held in registers pf[9][2]; l>=9 read from intact LDS)

__global__ __launch_bounds__(512, 2)
void attn_prop_kernel(const float* __restrict__ x, float* __restrict__ out)
{
    __shared__ __align__(16) unsigned char smem_raw[131072];
    __bf16* const p_lds = (__bf16*)smem_raw;
    __bf16* const s1    = (__bf16*)smem_raw;
    __bf16* const s2    = (__bf16*)smem_raw;

    const int tid  = threadIdx.x;
    const int wave = tid >> 6;
    const int lane = tid & 63;
    const int quad = lane >> 4;
    const int c16  = lane & 15;
    const int l0   = blockIdx.x * LT;

    const int seg = tid & 3;           // 16B segment of a 64B row: l = seg*4 + j
    // phase-1 staging map: lane owns rows (m1, cc0+0..15); R[r] = row (m1, cc0+r)
    const int sr1 = tid >> 2;          // 0..127
    const int m1  = sr1 >> 1;          // 0..63
    const int cc0 = (sr1 & 1) << 4;    // 0 or 16
    // phase-2 staging map: lane owns rows (m0+0..15, cc2); R[r] = row (m0+r, cc2)
    const int cc2 = (tid >> 2) & 31;
    const int m0  = (tid >> 7) << 4;   // 0,16,32,48

    // ================= phase 1: S = (A A^T)/sqrt(C); P' = softmax(S) + I ==========
    f32x4 acc[2][4][4];
#pragma unroll
    for (int ll = 0; ll < 2; ++ll)
#pragma unroll
        for (int i = 0; i < 4; ++i)
#pragma unroll
            for (int j = 0; j < 4; ++j)
                acc[ll][i][j] = (f32x4){0.f, 0.f, 0.f, 0.f};

    float4 R[16];   // cross-iteration prefetch buffer (64 VGPRs)

    // prologue: load chunk kc=0 (phase-1 map)
#pragma unroll
    for (int r = 0; r < 16; ++r)
        R[r] = *(const float4*)(x + ((m1 * NC + cc0 + r) * NL + l0) + (seg << 2));

    for (int kc = 0; kc < 16; ++kc) {
        __syncthreads();   // prev iter frag reads done before restage
        // store chunk kc: lane's cc-run -> 8 x ds_write_b128 (bank-floor pattern)
#pragma unroll
        for (int j = 0; j < 4; ++j) {
            const int l = seg * 4 + j;
#pragma unroll
            for (int h = 0; h < 2; ++h) {
                bf16x8 v;
#pragma unroll
                for (int k = 0; k < 8; ++k) v[k] = (__bf16)R[h * 8 + k][j];
                *(bf16x8*)(s1 + (l * 64 + m1) * 40 + cc0 + h * 8) = v;
            }
        }
        // issue prefetch of chunk kc+1; flies under MFMA + barriers
        if (kc < 15) {
            const int c0n = (kc + 1) * 32;
#pragma unroll
            for (int r = 0; r < 16; ++r)
                R[r] = *(const float4*)(x + ((m1 * NC + c0n + cc0 + r) * NL + l0) + (seg << 2));
        }
        __syncthreads();
#pragma unroll
        for (int ll = 0; ll < 2; ++ll) {
            const int l = wave * 2 + ll;
            bf16x8 a[4];
#pragma unroll
            for (int i = 0; i < 4; ++i)
                a[i] = *(const bf16x8*)(s1 + (l * 64 + i * 16 + c16) * 40 + quad * 8);
#pragma unroll
            for (int i = 0; i < 4; ++i)
#pragma unroll
                for (int j = 0; j < 4; ++j)
                    acc[ll][i][j] = __builtin_amdgcn_mfma_f32_16x16x32_bf16(
                        a[i], a[j], acc[ll][i][j], 0, 0, 0);
        }
    }

    // prefetch phase-2 chunk ch=0 (phase-2 map): hides under softmax + P' store + pf
#pragma unroll
    for (int r = 0; r < 16; ++r)
        R[r] = *(const float4*)(x + (((m0 + r) * NC + cc2) * NL + l0) + (seg << 2));

    __syncthreads();   // all frag reads of s1 done; safe to overwrite with P'

    // softmax rows n = 16i + 4*quad + q; cols m = 16j + c16
    const float rs = 0.04419417382415922f;   // 1/sqrt(512)
#pragma unroll
    for (int ll = 0; ll < 2; ++ll) {
        const int l = wave * 2 + ll;
#pragma unroll
        for (int i = 0; i < 4; ++i) {
#pragma unroll
            for (int q = 0; q < 4; ++q) {
                float s[4];
#pragma unroll
                for (int j = 0; j < 4; ++j) s[j] = acc[ll][i][j][q] * rs;
                float rmax = fmaxf(fmaxf(s[0], s[1]), fmaxf(s[2], s[3]));
#pragma unroll
                for (int d = 1; d <= 8; d <<= 1)
                    rmax = fmaxf(rmax, __shfl_xor(rmax, d, 64));
                float e[4], rsum = 0.f;
#pragma unroll
                for (int j = 0; j < 4; ++j) { e[j] = __expf(s[j] - rmax); rsum += e[j]; }
#pragma unroll
                for (int d = 1; d <= 8; d <<= 1)
                    rsum += __shfl_xor(rsum, d, 64);
                const float inv = 1.0f / rsum;
                const int n = i * 16 + quad * 4 + q;
#pragma unroll
                for (int j = 0; j < 4; ++j) {
                    float p = e[j] * inv;
                    if (i == j && (quad * 4 + q) == c16) p += 1.0f;  // P' = P + I
                    p_lds[l * 4096 + n * 64 + j * 16 + c16] = (__bf16)p;
                }
            }
        }
    }
    __syncthreads();

    // phase-2 wave assignment: wave -> (n-tile iw, c-subtile jw), all 16 l per wave.
    const int iw = wave & 3;
    const int jw = wave >> 2;
    bf16x8 pf[9][2];   // P' A-fragments for l = 0..8 (72 VGPRs); l>=9 stays in LDS
#pragma unroll
    for (int l = 0; l < 9; ++l)
#pragma unroll
        for (int k2 = 0; k2 < 2; ++k2)
            pf[l][k2] = *(const bf16x8*)(p_lds + l * 4096 + (iw * 16 + c16) * 64 + k2 * 32 + quad * 8);
    __syncthreads();   // pf loaded; s2 may overwrite P' l<=8 region

    // ================= phase 2: out = P' A (chunked over c) =======================
    for (int ch = 0; ch < 16; ++ch) {
        // store chunk ch: lane's m-run -> 8 x ds_write_b128 (bank-floor pattern)
#pragma unroll
        for (int j = 0; j < 4; ++j) {
            const int l = seg * 4 + j;
#pragma unroll
            for (int h = 0; h < 2; ++h) {
                bf16x8 v;
#pragma unroll
                for (int k = 0; k < 8; ++k) v[k] = (__bf16)R[h * 8 + k][j];
                *(bf16x8*)(s2 + cc2 * 1032 + l * 64 + m0 + h * 8) = v;
            }
        }
        // issue prefetch of chunk ch+1; flies under MFMA + out-stores
        if (ch < 15) {
            const int c0n = (ch + 1) * 32;
#pragma unroll
            for (int r = 0; r < 16; ++r)
                R[r] = *(const float4*)(x + (((m0 + r) * NC + c0n + cc2) * NL + l0) + (seg << 2));
        }
        __syncthreads();

        const int cg = ch * 32 + jw * 16 + c16;
#pragma unroll
        for (int h = 0; h < 2; ++h) {
            f32x4 acc2[8];
#pragma unroll
            for (int u = 0; u < 8; ++u) {
                const int l = h * 8 + u;
                f32x4 a2 = (f32x4){0.f, 0.f, 0.f, 0.f};
#pragma unroll
                for (int k2 = 0; k2 < 2; ++k2) {
                    bf16x8 pa;
                    if (l <= 8) pa = pf[l][k2];
                    else        pa = *(const bf16x8*)(p_lds + l * 4096 + (iw * 16 + c16) * 64 + k2 * 32 + quad * 8);
                    bf16x8 b = *(const bf16x8*)(s2 + (jw * 16 + c16) * 1032 + l * 64 + k2 * 32 + quad * 8);
                    a2 = __builtin_amdgcn_mfma_f32_16x16x32_bf16(pa, b, a2, 0, 0, 0);
                }
                acc2[u] = a2;
            }
#pragma unroll
            for (int q = 0; q < 4; ++q) {
                const int n = iw * 16 + quad * 4 + q;
                float* dst = out + ((n * NC + cg) * NL + l0) + h * 8;
                float4 w;
                w.x = acc2[0][q]; w.y = acc2[1][q]; w.z = acc2[2][q]; w.w = acc2[3][q];
                ((float4*)dst)[0] = w;
                w.x = acc2[4][q]; w.y = acc2[5][q]; w.z = acc2[6][q]; w.w = acc2[7][q];
                ((float4*)dst)[1] = w;
            }
        }
        __syncthreads();   // B-frag reads done before next restage
    }
}

extern "C" void kernel_launch(void* const* d_in, const int* in_sizes, int n_in,
                              void* d_out, int out_size, void* d_ws, size_t ws_size,
                              hipStream_t stream)
{
    const float* x = (const float*)d_in[0];
    float* o = (float*)d_out;
    attn_prop_kernel<<<dim3(NL / LT), dim3(512), 0, stream>>>(x, o);
}